// Round 4
// baseline (253.704 us; speedup 1.0000x reference)
//
#include <hip/hip_runtime.h>

#define IMG   384
#define NIMG  64
#define HALO  5
#define NW    4                 // waves per block (vertical)
#define RW    10                // rows per wave (register columns)
#define TH    (NW*RW)           // 40 tile rows
#define VY    (TH - 2*HALO)     // 30 valid rows per strip
#define VX    116               // valid cols per tile (x0 stays even)
#define GRIDX 4                 // 4*116 = 464 >= 384
#define GRIDY 13                // 13*30 = 390 >= 384
#define NPART (GRIDX*GRIDY*NIMG)

typedef float f32x2 __attribute__((ext_vector_type(2)));

static __device__ __forceinline__ f32x2 pk_add(f32x2 a, f32x2 b) {
    f32x2 d; asm("v_pk_add_f32 %0, %1, %2" : "=v"(d) : "v"(a), "v"(b)); return d;
}
// d.lo = a.lo + b.hi ; d.hi = a.hi + b.lo   (within-pair horizontal terms)
static __device__ __forceinline__ f32x2 pk_add_swap(f32x2 a, f32x2 b) {
    f32x2 d; asm("v_pk_add_f32 %0, %1, %2 op_sel:[0,1] op_sel_hi:[1,0]"
                 : "=v"(d) : "v"(a), "v"(b)); return d;
}
static __device__ __forceinline__ f32x2 pk_mul(f32x2 a, f32x2 b) {
    f32x2 d; asm("v_pk_mul_f32 %0, %1, %2" : "=v"(d) : "v"(a), "v"(b)); return d;
}
// lane i <- lane i-1, lane 0 gets 0 (WAVE_SHR1)
static __device__ __forceinline__ float dpp_sr1(float x) {
    return __int_as_float(
        __builtin_amdgcn_update_dpp(0, __float_as_int(x), 0x138, 0xF, 0xF, true));
}
// lane i <- lane i+1, lane 63 gets 0 (WAVE_SHL1)
static __device__ __forceinline__ float dpp_sl1(float x) {
    return __int_as_float(
        __builtin_amdgcn_update_dpp(0, __float_as_int(x), 0x130, 0xF, 0xF, true));
}

// __launch_bounds__(256, 8): 8 waves/EU -> 8 blocks/CU; caps VGPR at 64
// (HW VGPR quantum steps at 64 -> this is the 100%-occupancy bucket).
__global__ __launch_bounds__(256, 8) void boundary_bce_fused(
    const float* __restrict__ hand,
    const float* __restrict__ obj,
    const float* __restrict__ target,
    float* __restrict__ partial)
{
    const int tid  = threadIdx.x;
    const int lane = tid & 63;
    const int w    = tid >> 6;
    const int tx = blockIdx.x, ty = blockIdx.y, n = blockIdx.z;

    const int x0    = tx * VX - 6;          // even -> 8B-aligned pair loads
    const int y0    = ty * VY - HALO;
    const int gx0   = x0 + 2 * lane;        // this lane's column pair
    const int ybase = y0 + w * RW;

    const size_t ioff = (size_t)n * IMG * IMG;
    const float* __restrict__ hp = hand   + ioff;
    const float* __restrict__ op = obj    + ioff;
    const float* __restrict__ tp = target + ioff;

    // IMG even & gx0 even => a pair is fully in-image or fully out.
    const bool colok = (gx0 >= 0) & (gx0 < IMG);
    const float mc   = colok ? 1.f : 0.f;
    const f32x2 mcol = {mc, mc};
    const f32x2 zero = {0.f, 0.f};

    f32x2 h[RW], o[RW];
    #pragma unroll
    for (int r = 0; r < RW; ++r) {
        int gy = ybase + r;
        bool ok = colok & (gy >= 0) & (gy < IMG);
        size_t idx = (size_t)gy * IMG + gx0;
        h[r] = ok ? *(const f32x2*)(hp + idx) : zero;
        o[r] = ok ? *(const f32x2*)(op + idx) : zero;
    }

    // Rows gy==-1 / gy==IMG must be re-zeroed each iteration (zero padding
    // is reapplied per conv); junk farther out cannot cross a zeroed row
    // before the valid region ends. Constant register indices:
    //   ty==0:        gy=-1  -> tile row 4  -> w==0, r==4
    //   ty==GRIDY-1:  gy=384 -> tile row 29 -> w==2, r==9   (y0 = 355)
    const bool ztop = (ty == 0)         && (w == 0);
    const bool zbot = (ty == GRIDY - 1) && (w == 2);

    // inter-wave halo rows, double-buffered -> one barrier per iteration
    __shared__ f32x2 sTopH[2][NW][64], sBotH[2][NW][64];
    __shared__ f32x2 sTopO[2][NW][64], sBotO[2][NW][64];

    #pragma unroll 1
    for (int it = 0; it < 5; ++it) {
        const int b = it & 1;
        sTopH[b][w][lane] = h[0];  sBotH[b][w][lane] = h[RW-1];
        sTopO[b][w][lane] = o[0];  sBotO[b][w][lane] = o[RW-1];
        __syncthreads();

        f32x2 upH = (w > 0)      ? sBotH[b][w-1][lane] : zero;
        f32x2 upO = (w > 0)      ? sBotO[b][w-1][lane] : zero;
        f32x2 dnH = (w < NW - 1) ? sTopH[b][w+1][lane] : zero;
        f32x2 dnO = (w < NW - 1) ? sTopO[b][w+1][lane] : zero;

        f32x2 prevH = upH, prevO = upO;
        #pragma unroll
        for (int r = 0; r < RW; ++r) {
            f32x2 belowH = (r == RW - 1) ? dnH : h[r+1];
            f32x2 belowO = (r == RW - 1) ? dnO : o[r+1];
            f32x2 cH = h[r], cO = o[r];
            f32x2 vH = pk_add(pk_add(cH, prevH), belowH);   // vertical
            f32x2 vO = pk_add(pk_add(cO, prevO), belowO);
            f32x2 sH = pk_add_swap(vH, cH);                 // in-pair horizontal
            f32x2 sO = pk_add_swap(vO, cO);
            sH.x += dpp_sr1(cH.y); sH.y += dpp_sl1(cH.x);   // cross-pair terms
            sO.x += dpp_sr1(cO.y); sO.y += dpp_sl1(cO.x);
            sH.x = fminf(sH.x, 1.f); sH.y = fminf(sH.y, 1.f);
            sO.x = fminf(sO.x, 1.f); sO.y = fminf(sO.y, 1.f);
            h[r] = pk_mul(sH, mcol);                        // col zero-padding
            o[r] = pk_mul(sO, mcol);
            prevH = cH; prevO = cO;
        }
        if (ztop) { h[4] = zero; o[4] = zero; }
        if (zbot) { h[9] = zero; o[9] = zero; }
        // no 2nd barrier: next iter writes the other LDS buffer
    }

    // ---- BCE: lanes 3..60, tile rows 5..34, gy < IMG.
    // Accumulate in log2 space; finalize scales by ln2 once.
    const float C = -144.26950408889634f;   // -100 / ln2
    float psum = 0.f;
    const bool lane_ok = colok & (lane >= 3) & (lane <= 60);
    #pragma unroll
    for (int r = 0; r < RW; ++r) {
        int ly = w * RW + r;
        int gy = ybase + r;
        bool v = lane_ok & (ly >= HALO) & (ly <= TH - 1 - HALO) & (gy < IMG);
        if (v) {
            f32x2 p = pk_mul(h[r], o[r]);
            f32x2 t = *(const f32x2*)(tp + (size_t)gy * IMG + gx0);
            float lp0  = fmaxf(__log2f(p.x),       C);
            float l1p0 = fmaxf(__log2f(1.f - p.x), C);
            float lp1  = fmaxf(__log2f(p.y),       C);
            float l1p1 = fmaxf(__log2f(1.f - p.y), C);
            psum += t.x * lp0 + (1.f - t.x) * l1p0;
            psum += t.y * lp1 + (1.f - t.y) * l1p1;
        }
    }

    #pragma unroll
    for (int off = 32; off > 0; off >>= 1)
        psum += __shfl_down(psum, off, 64);
    __shared__ float wsum[NW];
    if (lane == 0) wsum[w] = psum;
    __syncthreads();
    if (tid == 0) {
        partial[blockIdx.x + GRIDX * (blockIdx.y + GRIDY * blockIdx.z)] =
            wsum[0] + wsum[1] + wsum[2] + wsum[3];
    }
}

__global__ __launch_bounds__(256) void boundary_bce_finalize(
    const float* __restrict__ partial, float* __restrict__ out)
{
    float s = 0.f;
    for (int i = threadIdx.x; i < NPART; i += 256) s += partial[i];
    #pragma unroll
    for (int off = 32; off > 0; off >>= 1)
        s += __shfl_down(s, off, 64);
    __shared__ float ws[4];
    if ((threadIdx.x & 63) == 0) ws[threadIdx.x >> 6] = s;
    __syncthreads();
    if (threadIdx.x == 0) {
        const float LN2 = 0.69314718055994531f;
        float tot = ws[0] + ws[1] + ws[2] + ws[3];
        out[0] = -(tot * LN2) / (float)((size_t)NIMG * IMG * IMG);
    }
}

extern "C" void kernel_launch(void* const* d_in, const int* in_sizes, int n_in,
                              void* d_out, int out_size, void* d_ws, size_t ws_size,
                              hipStream_t stream)
{
    const float* hand   = (const float*)d_in[0];
    const float* obj    = (const float*)d_in[1];
    const float* target = (const float*)d_in[2];
    float* partial = (float*)d_ws;   // NPART floats, every slot written each call

    dim3 grid(GRIDX, GRIDY, NIMG);   // 4 x 13 x 64 = 3328 blocks
    boundary_bce_fused<<<grid, 256, 0, stream>>>(hand, obj, target, partial);
    boundary_bce_finalize<<<1, 256, 0, stream>>>(partial, (float*)d_out);
}

// Round 5
// 146.543 us; speedup vs baseline: 1.7313x; 1.7313x over previous
//
#include <hip/hip_runtime.h>

#define IMG   384
#define NIMG  64
#define HALO  5
#define NW    4                 // waves per block (vertical)
#define RW    10                // rows per wave (register columns)
#define TH    (NW*RW)           // 40 tile rows
#define VY    (TH - 2*HALO)     // 30 valid rows per strip
#define VX    116               // valid cols per tile (x0 stays even)
#define GRIDX 4                 // 4*116 = 464 >= 384
#define GRIDY 13                // 13*30 = 390 >= 384
#define NPART (GRIDX*GRIDY*NIMG)

typedef float f32x2 __attribute__((ext_vector_type(2)));

static __device__ __forceinline__ f32x2 pk_add(f32x2 a, f32x2 b) {
    f32x2 d; asm("v_pk_add_f32 %0, %1, %2" : "=v"(d) : "v"(a), "v"(b)); return d;
}
// d.lo = a.lo + b.hi ; d.hi = a.hi + b.lo   (within-pair horizontal terms)
static __device__ __forceinline__ f32x2 pk_add_swap(f32x2 a, f32x2 b) {
    f32x2 d; asm("v_pk_add_f32 %0, %1, %2 op_sel:[0,1] op_sel_hi:[1,0]"
                 : "=v"(d) : "v"(a), "v"(b)); return d;
}
static __device__ __forceinline__ f32x2 pk_mul(f32x2 a, f32x2 b) {
    f32x2 d; asm("v_pk_mul_f32 %0, %1, %2" : "=v"(d) : "v"(a), "v"(b)); return d;
}
// lane i <- lane i-1, lane 0 gets 0 (WAVE_SHR1)
static __device__ __forceinline__ float dpp_sr1(float x) {
    return __int_as_float(
        __builtin_amdgcn_update_dpp(0, __float_as_int(x), 0x138, 0xF, 0xF, true));
}
// lane i <- lane i+1, lane 63 gets 0 (WAVE_SHL1)
static __device__ __forceinline__ float dpp_sl1(float x) {
    return __int_as_float(
        __builtin_amdgcn_update_dpp(0, __float_as_int(x), 0x130, 0xF, 0xF, true));
}

// __launch_bounds__(256, 4): 128-VGPR budget. Working set is ~104 VGPRs
// (h/o register arrays = 40) -> NO SPILL (round 4's (256,8) forced 64 and
// spilled to scratch: WRITE_SIZE 0.04->304 MB, 2.2x regression).
// floor(512/104) = 4 waves/SIMD cap either way; TLP comes from the
// 3328-block grid (13 blocks/CU of work, ~3.25 full GPU fills).
__global__ __launch_bounds__(256, 4) void boundary_bce_fused(
    const float* __restrict__ hand,
    const float* __restrict__ obj,
    const float* __restrict__ target,
    float* __restrict__ partial)
{
    const int tid  = threadIdx.x;
    const int lane = tid & 63;
    const int w    = tid >> 6;
    const int tx = blockIdx.x, ty = blockIdx.y, n = blockIdx.z;

    const int x0    = tx * VX - 6;          // even -> 8B-aligned pair loads
    const int y0    = ty * VY - HALO;
    const int gx0   = x0 + 2 * lane;        // this lane's column pair
    const int ybase = y0 + w * RW;

    const size_t ioff = (size_t)n * IMG * IMG;
    const float* __restrict__ hp = hand   + ioff;
    const float* __restrict__ op = obj    + ioff;
    const float* __restrict__ tp = target + ioff;

    // IMG even & gx0 even => a pair is fully in-image or fully out.
    const bool colok = (gx0 >= 0) & (gx0 < IMG);
    const float mc   = colok ? 1.f : 0.f;
    const f32x2 mcol = {mc, mc};
    const f32x2 zero = {0.f, 0.f};

    f32x2 h[RW], o[RW];
    #pragma unroll
    for (int r = 0; r < RW; ++r) {
        int gy = ybase + r;
        bool ok = colok & (gy >= 0) & (gy < IMG);
        size_t idx = (size_t)gy * IMG + gx0;
        h[r] = ok ? *(const f32x2*)(hp + idx) : zero;
        o[r] = ok ? *(const f32x2*)(op + idx) : zero;
    }

    // Rows gy==-1 / gy==IMG must be re-zeroed each iteration (zero padding
    // is reapplied per conv); junk farther out cannot cross a zeroed row
    // before the valid region ends. Constant register indices:
    //   ty==0:        gy=-1  -> tile row 4  -> w==0, r==4
    //   ty==GRIDY-1:  gy=384 -> tile row 29 -> w==2, r==9   (y0 = 355)
    const bool ztop = (ty == 0)         && (w == 0);
    const bool zbot = (ty == GRIDY - 1) && (w == 2);

    // inter-wave halo rows, double-buffered -> one barrier per iteration
    __shared__ f32x2 sTopH[2][NW][64], sBotH[2][NW][64];
    __shared__ f32x2 sTopO[2][NW][64], sBotO[2][NW][64];

    #pragma unroll 1
    for (int it = 0; it < 5; ++it) {
        const int b = it & 1;
        sTopH[b][w][lane] = h[0];  sBotH[b][w][lane] = h[RW-1];
        sTopO[b][w][lane] = o[0];  sBotO[b][w][lane] = o[RW-1];
        __syncthreads();

        f32x2 upH = (w > 0)      ? sBotH[b][w-1][lane] : zero;
        f32x2 upO = (w > 0)      ? sBotO[b][w-1][lane] : zero;
        f32x2 dnH = (w < NW - 1) ? sTopH[b][w+1][lane] : zero;
        f32x2 dnO = (w < NW - 1) ? sTopO[b][w+1][lane] : zero;

        f32x2 prevH = upH, prevO = upO;
        #pragma unroll
        for (int r = 0; r < RW; ++r) {
            f32x2 belowH = (r == RW - 1) ? dnH : h[r+1];
            f32x2 belowO = (r == RW - 1) ? dnO : o[r+1];
            f32x2 cH = h[r], cO = o[r];
            f32x2 vH = pk_add(pk_add(cH, prevH), belowH);   // vertical
            f32x2 vO = pk_add(pk_add(cO, prevO), belowO);
            f32x2 sH = pk_add_swap(vH, cH);                 // in-pair horizontal
            f32x2 sO = pk_add_swap(vO, cO);
            sH.x += dpp_sr1(cH.y); sH.y += dpp_sl1(cH.x);   // cross-pair terms
            sO.x += dpp_sr1(cO.y); sO.y += dpp_sl1(cO.x);
            sH.x = fminf(sH.x, 1.f); sH.y = fminf(sH.y, 1.f);
            sO.x = fminf(sO.x, 1.f); sO.y = fminf(sO.y, 1.f);
            h[r] = pk_mul(sH, mcol);                        // col zero-padding
            o[r] = pk_mul(sO, mcol);
            prevH = cH; prevO = cO;
        }
        if (ztop) { h[4] = zero; o[4] = zero; }
        if (zbot) { h[9] = zero; o[9] = zero; }
        // no 2nd barrier: next iter writes the other LDS buffer
    }

    // ---- BCE: lanes 3..60, tile rows 5..34, gy < IMG.
    // Accumulate in log2 space; finalize scales by ln2 once.
    const float C = -144.26950408889634f;   // -100 / ln2
    float psum = 0.f;
    const bool lane_ok = colok & (lane >= 3) & (lane <= 60);
    #pragma unroll
    for (int r = 0; r < RW; ++r) {
        int ly = w * RW + r;
        int gy = ybase + r;
        bool v = lane_ok & (ly >= HALO) & (ly <= TH - 1 - HALO) & (gy < IMG);
        if (v) {
            f32x2 p = pk_mul(h[r], o[r]);
            f32x2 t = *(const f32x2*)(tp + (size_t)gy * IMG + gx0);
            float lp0  = fmaxf(__log2f(p.x),       C);
            float l1p0 = fmaxf(__log2f(1.f - p.x), C);
            float lp1  = fmaxf(__log2f(p.y),       C);
            float l1p1 = fmaxf(__log2f(1.f - p.y), C);
            psum += t.x * lp0 + (1.f - t.x) * l1p0;
            psum += t.y * lp1 + (1.f - t.y) * l1p1;
        }
    }

    #pragma unroll
    for (int off = 32; off > 0; off >>= 1)
        psum += __shfl_down(psum, off, 64);
    __shared__ float wsum[NW];
    if (lane == 0) wsum[w] = psum;
    __syncthreads();
    if (tid == 0) {
        partial[blockIdx.x + GRIDX * (blockIdx.y + GRIDY * blockIdx.z)] =
            wsum[0] + wsum[1] + wsum[2] + wsum[3];
    }
}

__global__ __launch_bounds__(256) void boundary_bce_finalize(
    const float* __restrict__ partial, float* __restrict__ out)
{
    float s = 0.f;
    for (int i = threadIdx.x; i < NPART; i += 256) s += partial[i];
    #pragma unroll
    for (int off = 32; off > 0; off >>= 1)
        s += __shfl_down(s, off, 64);
    __shared__ float ws[4];
    if ((threadIdx.x & 63) == 0) ws[threadIdx.x >> 6] = s;
    __syncthreads();
    if (threadIdx.x == 0) {
        const float LN2 = 0.69314718055994531f;
        float tot = ws[0] + ws[1] + ws[2] + ws[3];
        out[0] = -(tot * LN2) / (float)((size_t)NIMG * IMG * IMG);
    }
}

extern "C" void kernel_launch(void* const* d_in, const int* in_sizes, int n_in,
                              void* d_out, int out_size, void* d_ws, size_t ws_size,
                              hipStream_t stream)
{
    const float* hand   = (const float*)d_in[0];
    const float* obj    = (const float*)d_in[1];
    const float* target = (const float*)d_in[2];
    float* partial = (float*)d_ws;   // NPART floats, every slot written each call

    dim3 grid(GRIDX, GRIDY, NIMG);   // 4 x 13 x 64 = 3328 blocks
    boundary_bce_fused<<<grid, 256, 0, stream>>>(hand, obj, target, partial);
    boundary_bce_finalize<<<1, 256, 0, stream>>>(partial, (float*)d_out);
}